// Round 8
// baseline (586.368 us; speedup 1.0000x reference)
//
#include <hip/hip_runtime.h>

// ============================================================================
// Fused 2-layer transformer encoder (B=1024, T=128, D=128, H=8, HD=16, FF=512)
// One workgroup per batch element; bf16 MFMA 16x16x32; fp32 accum/softmax/LN.
// Transposed orientation (Y^T = W*X^T) -> ushort4 C-fragment stores.
//
// Latency revision (R7 post-mortem: nothing saturated -> barrier/dependency
// bound). 512 threads / 8 waves (R1's high-ILP shape, 8 tiles per wave):
//  - Phase A: wave w computes head w's q,k,v (8 row-tiles each) -> no barrier
//    between A and B (own-wave lgkmcnt only).
//  - Phase B: kfr[8] (permuted rows, mask folded) + vfr[4] hoisted once,
//    reused across 8 q-tiles; zero-shuffle PV (R7-validated); max-free
//    softmax (R6-validated).
//  - Phases C/E are BY-M (wave owns row-tile w): LayerNorm row stats are
//    fully in-register (32 local + 2 shfl_xor) -> the 2-barrier + serial
//    tid<128 LN dance is DELETED (x2 per layer). B-fragments (o / hidden)
//    hoisted once, reused across all 8 col-tiles; weights read per-col-tile
//    from L2 (VMEM pipe is idle).
//  - FF: 2 chunks of 256; FF1 by-N (2 col-tiles/wave), FF2 by-M.
//  - 6 barriers/layer vs ~11.
// ============================================================================

typedef __attribute__((ext_vector_type(8))) __bf16 bf16x8;
typedef __attribute__((ext_vector_type(4))) float fx4;

#define MFMA16(a, b, c) __builtin_amdgcn_mfma_f32_16x16x32_bf16((a), (b), (c), 0, 0, 0)

// padded LDS strides (elements); dword stride ≡ 4 mod 32 -> 2-way (free)
#define XS_S 136
#define QS_S 136
#define KS_S 136
#define VT_S 136
#define HS2  264     // FF hidden [128][264] chunk (aliases k|v^T region)

static __device__ __forceinline__ unsigned short f2bf(float f) {
    __bf16 b = (__bf16)f;                       // fptrunc f32->bf16, RTN-even
    return __builtin_bit_cast(unsigned short, b);
}
static __device__ __forceinline__ float bf2f(unsigned short u) {
    return (float)__builtin_bit_cast(__bf16, u);
}
static __device__ __forceinline__ unsigned pk2(float a, float b) {
    return (unsigned)f2bf(a) | ((unsigned)f2bf(b) << 16);
}
static __device__ __forceinline__ bf16x8 mk8(unsigned d0, unsigned d1,
                                             unsigned d2, unsigned d3) {
    union { unsigned u[4]; bf16x8 v; } c;
    c.u[0] = d0; c.u[1] = d1; c.u[2] = d2; c.u[3] = d3;
    return c.v;
}

// --------------------------------------------------------------------------
// Prep: convert all fp32 weights to bf16 into workspace.
// Segments (elements): in_proj 98304 | out 32768 | ff1 131072 | ff2 131072
// --------------------------------------------------------------------------
extern "C" __global__ void prep_weights_bf16(const float* __restrict__ w_in,
                                             const float* __restrict__ w_out,
                                             const float* __restrict__ w_ff1,
                                             const float* __restrict__ w_ff2,
                                             unsigned short* __restrict__ ws) {
    int i = blockIdx.x * 256 + threadIdx.x;     // grid covers exactly 393216
    float v;
    if (i < 98304)       v = w_in[i];
    else if (i < 131072) v = w_out[i - 98304];
    else if (i < 262144) v = w_ff1[i - 131072];
    else                 v = w_ff2[i - 262144];
    ws[i] = f2bf(v);
}

// --------------------------------------------------------------------------
// Main fused kernel. block = 512 threads = 8 waves. grid = 1024 (one per b).
// __launch_bounds__(512,2): RA budget 256, never spills (R1/R4-proven).
// --------------------------------------------------------------------------
extern "C" __global__ void __launch_bounds__(512, 2)
fused_transformer(const float* __restrict__ x,
                  const float* __restrict__ mask,
                  const float* __restrict__ inp_b,
                  const float* __restrict__ out_b,
                  const float* __restrict__ ln1g, const float* __restrict__ ln1b,
                  const float* __restrict__ ff1b, const float* __restrict__ ff2b,
                  const float* __restrict__ ln2g, const float* __restrict__ ln2b,
                  const unsigned short* __restrict__ w_inp,
                  const unsigned short* __restrict__ w_out,
                  const unsigned short* __restrict__ w_ff1,
                  const unsigned short* __restrict__ w_ff2,
                  float* __restrict__ out) {
    // ~139 KiB static LDS (1 block/CU)
    __shared__ __align__(16) unsigned short xs[128 * XS_S];      // x / LN out [t][d]
    __shared__ __align__(16) unsigned short qs[128 * QS_S];      // q -> o     [t][d]
    __shared__ __align__(16) unsigned short kvh[2 * 128 * KS_S]; // k | v^T ; FF hidden
    __shared__ __align__(16) unsigned short mlds[128];           // mask (bf16)

    unsigned short* ksb = kvh;                 // k   [t][d]    stride KS_S
    unsigned short* vtb = kvh + 128 * KS_S;    // v^T [d][t]    stride VT_S
    unsigned short* hb  = kvh;                 // FF hidden [t][256] stride HS2

    const int tid = threadIdx.x;
    const int w   = tid >> 6;        // wave 0..7 == head (B) == row-tile (C/E)
    const int lid = tid & 63;
    const int l15 = lid & 15;
    const int kg  = lid >> 4;        // k-group 0..3
    const int b   = blockIdx.x;
    const int h   = w;

    // ---- stage x[b] (fp32) -> xs (bf16), and mask[b] -> mlds (bf16) ----
    const float* xb = x + (size_t)b * 16384;
    #pragma unroll
    for (int i = 0; i < 8; ++i) {
        int e = i * 2048 + tid * 4;
        float4 v4 = *(const float4*)(xb + e);
        int row = e >> 7, col = e & 127;
        ushort4 pk;
        pk.x = f2bf(v4.x); pk.y = f2bf(v4.y); pk.z = f2bf(v4.z); pk.w = f2bf(v4.w);
        *(ushort4*)(xs + row * XS_S + col) = pk;
    }
    if (tid < 128) mlds[tid] = f2bf(mask[b * 128 + tid]);
    __syncthreads();

    for (int l = 0; l < 2; ++l) {
        // ===== Phase A: head h's q,k,v by its own wave (8 row-tiles each) ===
        {
            const unsigned short* wbase = w_inp + (size_t)l * 49152;
            {   // Q
                bf16x8 wq[4];
                #pragma unroll
                for (int ks = 0; ks < 4; ++ks)
                    wq[ks] = *(const bf16x8*)(wbase + (h * 16 + l15) * 128 + ks * 32 + kg * 8);
                fx4 bq = *(const fx4*)(inp_b + l * 384 + h * 16 + kg * 4);
                #pragma unroll
                for (int mt = 0; mt < 8; ++mt) {
                    int trow = mt * 16 + l15;
                    bf16x8 xf[4];
                    #pragma unroll
                    for (int ks = 0; ks < 4; ++ks)
                        xf[ks] = *(const bf16x8*)(xs + trow * XS_S + ks * 32 + kg * 8);
                    fx4 a = bq;
                    #pragma unroll
                    for (int ks = 0; ks < 4; ++ks) a = MFMA16(wq[ks], xf[ks], a);
                    ushort4 p4;   // pre-scaled by 1/sqrt(HD)=0.25 (exact in bf16)
                    p4.x = f2bf(a[0] * 0.25f); p4.y = f2bf(a[1] * 0.25f);
                    p4.z = f2bf(a[2] * 0.25f); p4.w = f2bf(a[3] * 0.25f);
                    *(ushort4*)(qs + trow * QS_S + h * 16 + kg * 4) = p4;
                }
            }
            {   // K
                bf16x8 wk[4];
                #pragma unroll
                for (int ks = 0; ks < 4; ++ks)
                    wk[ks] = *(const bf16x8*)(wbase + (128 + h * 16 + l15) * 128 + ks * 32 + kg * 8);
                fx4 bk = *(const fx4*)(inp_b + l * 384 + 128 + h * 16 + kg * 4);
                #pragma unroll
                for (int mt = 0; mt < 8; ++mt) {
                    int trow = mt * 16 + l15;
                    bf16x8 xf[4];
                    #pragma unroll
                    for (int ks = 0; ks < 4; ++ks)
                        xf[ks] = *(const bf16x8*)(xs + trow * XS_S + ks * 32 + kg * 8);
                    fx4 a = bk;
                    #pragma unroll
                    for (int ks = 0; ks < 4; ++ks) a = MFMA16(wk[ks], xf[ks], a);
                    ushort4 p4;
                    p4.x = f2bf(a[0]); p4.y = f2bf(a[1]);
                    p4.z = f2bf(a[2]); p4.w = f2bf(a[3]);
                    *(ushort4*)(ksb + trow * KS_S + h * 16 + kg * 4) = p4;
                }
            }
            {   // V (transposed store)
                bf16x8 wv[4];
                #pragma unroll
                for (int ks = 0; ks < 4; ++ks)
                    wv[ks] = *(const bf16x8*)(wbase + (256 + h * 16 + l15) * 128 + ks * 32 + kg * 8);
                float bv = inp_b[l * 384 + 256 + h * 16 + l15];
                #pragma unroll
                for (int mt = 0; mt < 8; ++mt) {
                    int trow = mt * 16 + l15;
                    bf16x8 xf[4];
                    #pragma unroll
                    for (int ks = 0; ks < 4; ++ks)
                        xf[ks] = *(const bf16x8*)(xs + trow * XS_S + ks * 32 + kg * 8);
                    fx4 a = {bv, bv, bv, bv};
                    #pragma unroll
                    for (int ks = 0; ks < 4; ++ks) a = MFMA16(xf[ks], wv[ks], a);
                    ushort4 p4;
                    p4.x = f2bf(a[0]); p4.y = f2bf(a[1]);
                    p4.z = f2bf(a[2]); p4.w = f2bf(a[3]);
                    *(ushort4*)(vtb + (h * 16 + l15) * VT_S + mt * 16 + kg * 4) = p4;
                }
            }
        }
        // own-wave q/k/v write -> read: drain DS queue, NO barrier needed
        asm volatile("s_waitcnt lgkmcnt(0)" ::: "memory");

        // ===== Phase B: attention, hoisted K/V, zero-shuffle PV =============
        {
            // permuted base row: MFMA row m -> key offset (m>>2)*8 + (m&3)
            const int r0 = ((l15 >> 2) << 3) + (l15 & 3);
            bf16x8 kfr[8];
            #pragma unroll
            for (int kt = 0; kt < 8; ++kt) {
                int krow = (kt >> 1) * 32 + (kt & 1) * 4 + r0;
                bf16x8 f = {};
                if (kg < 2)
                    f = *(const bf16x8*)(ksb + krow * KS_S + h * 16 + kg * 8);
                else if (kg == 2)
                    f[0] = __builtin_bit_cast(__bf16, mlds[krow]);
                kfr[kt] = f;
            }
            bf16x8 vfr[4];
            #pragma unroll
            for (int s = 0; s < 4; ++s)
                vfr[s] = *(const bf16x8*)(vtb + (h * 16 + l15) * VT_S + s * 32 + kg * 8);

            #pragma unroll 1
            for (int qt = 0; qt < 8; ++qt) {
                int qrow = qt * 16 + l15;
                bf16x8 qf = {};
                if (kg < 2) qf = *(const bf16x8*)(qs + qrow * QS_S + h * 16 + kg * 8);
                else if (kg == 2) qf[0] = (__bf16)1.0f;  // ones column -> adds mask
                // S^T: sc[2s][r]=key s*32+kg*8+r, sc[2s+1][r]=key s*32+kg*8+4+r
                fx4 sc[8];
                #pragma unroll
                for (int kt = 0; kt < 8; ++kt) {
                    fx4 z = {0.f, 0.f, 0.f, 0.f};
                    sc[kt] = MFMA16(kfr[kt], qf, z);
                }
                // max-free softmax (scores O(1); masked keys exp(-1e9)=0)
                float sm = 0.f;
                #pragma unroll
                for (int kt = 0; kt < 8; ++kt)
                    #pragma unroll
                    for (int r = 0; r < 4; ++r) {
                        float e = __expf(sc[kt][r]);
                        sc[kt][r] = e;
                        sm += e;
                    }
                sm += __shfl_xor(sm, 16, 64);
                sm += __shfl_xor(sm, 32, 64);
                float inv = 1.f / sm;
                // PV: B-fragment is a pure in-register pack (no shuffles)
                fx4 oacc = {0.f, 0.f, 0.f, 0.f};
                #pragma unroll
                for (int s = 0; s < 4; ++s) {
                    bf16x8 pf = mk8(pk2(sc[2*s][0],   sc[2*s][1]),
                                    pk2(sc[2*s][2],   sc[2*s][3]),
                                    pk2(sc[2*s+1][0], sc[2*s+1][1]),
                                    pk2(sc[2*s+1][2], sc[2*s+1][3]));
                    oacc = MFMA16(vfr[s], pf, oacc);    // O^T = V^T * P^T (unnorm.)
                }
                ushort4 po;
                po.x = f2bf(oacc[0] * inv); po.y = f2bf(oacc[1] * inv);
                po.z = f2bf(oacc[2] * inv); po.w = f2bf(oacc[3] * inv);
                *(ushort4*)(qs + qrow * QS_S + h * 16 + kg * 4) = po;
            }
        }
        __syncthreads();

        // ===== Phase C (by-M): out-proj + residual + in-register LN1 ========
        {
            const int trow = w * 16 + l15;        // wave owns rows w*16..+15
            bf16x8 of[4];                          // o B-fragments, reused x8
            #pragma unroll
            for (int ks = 0; ks < 4; ++ks)
                of[ks] = *(const bf16x8*)(qs + trow * QS_S + ks * 32 + kg * 8);
            fx4 acc[8];
            #pragma unroll
            for (int i = 0; i < 8; ++i) {
                bf16x8 wof[4];
                #pragma unroll
                for (int ks = 0; ks < 4; ++ks)
                    wof[ks] = *(const bf16x8*)(w_out + (size_t)(l * 128 + i * 16 + l15) * 128
                                               + ks * 32 + kg * 8);
                fx4 a = *(const fx4*)(out_b + l * 128 + i * 16 + kg * 4);
                #pragma unroll
                for (int ks = 0; ks < 4; ++ks) a = MFMA16(wof[ks], of[ks], a);
                ushort4 rx = *(const ushort4*)(xs + trow * XS_S + i * 16 + kg * 4);
                a[0] += bf2f(rx.x); a[1] += bf2f(rx.y);
                a[2] += bf2f(rx.z); a[3] += bf2f(rx.w);
                acc[i] = a;
            }
            // in-register LN: 32 local values + 2 shuffles across kg
            float s = 0.f, qq = 0.f;
            #pragma unroll
            for (int i = 0; i < 8; ++i)
                #pragma unroll
                for (int r = 0; r < 4; ++r) { s += acc[i][r]; qq += acc[i][r] * acc[i][r]; }
            s  += __shfl_xor(s, 16, 64);  qq += __shfl_xor(qq, 16, 64);
            s  += __shfl_xor(s, 32, 64);  qq += __shfl_xor(qq, 32, 64);
            float mean = s * 0.0078125f;
            float rstd = rsqrtf(qq * 0.0078125f - mean * mean + 1e-5f);
            #pragma unroll
            for (int i = 0; i < 8; ++i) {
                fx4 g4 = *(const fx4*)(ln1g + l * 128 + i * 16 + kg * 4);
                fx4 b4 = *(const fx4*)(ln1b + l * 128 + i * 16 + kg * 4);
                ushort4 px;
                px.x = f2bf((acc[i][0] - mean) * rstd * g4[0] + b4[0]);
                px.y = f2bf((acc[i][1] - mean) * rstd * g4[1] + b4[1]);
                px.z = f2bf((acc[i][2] - mean) * rstd * g4[2] + b4[2]);
                px.w = f2bf((acc[i][3] - mean) * rstd * g4[3] + b4[3]);
                *(ushort4*)(xs + trow * XS_S + i * 16 + kg * 4) = px;
            }
        }
        __syncthreads();

        // ===== Phase D: FF, 2 chunks of 256; FF1 by-N, FF2 by-M =============
        fx4 yacc[8];
        {
            fx4 z = {0.f, 0.f, 0.f, 0.f};
            #pragma unroll
            for (int i = 0; i < 8; ++i) yacc[i] = z;
        }
        #pragma unroll 1
        for (int c = 0; c < 2; ++c) {
            {   // FF1: wave w -> hidden col-tiles {2w, 2w+1} of this chunk
                int frow = l * 512 + c * 256 + w * 32;
                bf16x8 w1f[2][4];
                fx4 b1f[2];
                #pragma unroll
                for (int u = 0; u < 2; ++u) {
                    #pragma unroll
                    for (int ks = 0; ks < 4; ++ks)
                        w1f[u][ks] = *(const bf16x8*)(w_ff1
                                        + (size_t)(frow + u * 16 + l15) * 128
                                        + ks * 32 + kg * 8);
                    b1f[u] = *(const fx4*)(ff1b + frow + u * 16 + kg * 4);
                }
                #pragma unroll
                for (int tt = 0; tt < 8; ++tt) {
                    int trow = tt * 16 + l15;
                    bf16x8 xf[4];
                    #pragma unroll
                    for (int ks = 0; ks < 4; ++ks)
                        xf[ks] = *(const bf16x8*)(xs + trow * XS_S + ks * 32 + kg * 8);
                    #pragma unroll
                    for (int u = 0; u < 2; ++u) {
                        fx4 a = b1f[u];
                        #pragma unroll
                        for (int ks = 0; ks < 4; ++ks) a = MFMA16(w1f[u][ks], xf[ks], a);
                        ushort4 ph;
                        ph.x = f2bf(fmaxf(a[0], 0.f)); ph.y = f2bf(fmaxf(a[1], 0.f));
                        ph.z = f2bf(fmaxf(a[2], 0.f)); ph.w = f2bf(fmaxf(a[3], 0.f));
                        *(ushort4*)(hb + trow * HS2 + w * 32 + u * 16 + kg * 4) = ph;
                    }
                }
            }
            __syncthreads();
            {   // FF2 by-M: hidden B-fragments hoisted, reused across 8 i
                const int trow = w * 16 + l15;
                bf16x8 hfr[8];
                #pragma unroll
                for (int k8 = 0; k8 < 8; ++k8)
                    hfr[k8] = *(const bf16x8*)(hb + trow * HS2 + k8 * 32 + kg * 8);
                #pragma unroll
                for (int i = 0; i < 8; ++i) {
                    #pragma unroll
                    for (int k8 = 0; k8 < 8; ++k8) {
                        bf16x8 w2 = *(const bf16x8*)(w_ff2
                                        + (size_t)(l * 128 + i * 16 + l15) * 512
                                        + c * 256 + k8 * 32 + kg * 8);
                        yacc[i] = MFMA16(w2, hfr[k8], yacc[i]);
                    }
                }
            }
            if (c == 0) __syncthreads();   // protect hidden before chunk 1
        }

        // ===== Phase E (by-M): bias + residual + in-register LN2 (+output) ==
        {
            const int trow = w * 16 + l15;
            #pragma unroll
            for (int i = 0; i < 8; ++i) {
                fx4 fb4 = *(const fx4*)(ff2b + l * 128 + i * 16 + kg * 4);
                ushort4 rx = *(const ushort4*)(xs + trow * XS_S + i * 16 + kg * 4);
                yacc[i][0] += fb4[0] + bf2f(rx.x);
                yacc[i][1] += fb4[1] + bf2f(rx.y);
                yacc[i][2] += fb4[2] + bf2f(rx.z);
                yacc[i][3] += fb4[3] + bf2f(rx.w);
            }
            float s = 0.f, qq = 0.f;
            #pragma unroll
            for (int i = 0; i < 8; ++i)
                #pragma unroll
                for (int r = 0; r < 4; ++r) { s += yacc[i][r]; qq += yacc[i][r] * yacc[i][r]; }
            s  += __shfl_xor(s, 16, 64);  qq += __shfl_xor(qq, 16, 64);
            s  += __shfl_xor(s, 32, 64);  qq += __shfl_xor(qq, 32, 64);
            float mean = s * 0.0078125f;
            float rstd = rsqrtf(qq * 0.0078125f - mean * mean + 1e-5f);
            if (l == 1) {   // final layer: fp32 output
                float* op = out + (size_t)b * 16384 + (size_t)trow * 128;
                #pragma unroll
                for (int i = 0; i < 8; ++i) {
                    fx4 g4 = *(const fx4*)(ln2g + l * 128 + i * 16 + kg * 4);
                    fx4 b4 = *(const fx4*)(ln2b + l * 128 + i * 16 + kg * 4);
                    float4 v4;
                    v4.x = (yacc[i][0] - mean) * rstd * g4[0] + b4[0];
                    v4.y = (yacc[i][1] - mean) * rstd * g4[1] + b4[1];
                    v4.z = (yacc[i][2] - mean) * rstd * g4[2] + b4[2];
                    v4.w = (yacc[i][3] - mean) * rstd * g4[3] + b4[3];
                    *(float4*)(op + i * 16 + kg * 4) = v4;
                }
            } else {
                #pragma unroll
                for (int i = 0; i < 8; ++i) {
                    fx4 g4 = *(const fx4*)(ln2g + l * 128 + i * 16 + kg * 4);
                    fx4 b4 = *(const fx4*)(ln2b + l * 128 + i * 16 + kg * 4);
                    ushort4 px;
                    px.x = f2bf((yacc[i][0] - mean) * rstd * g4[0] + b4[0]);
                    px.y = f2bf((yacc[i][1] - mean) * rstd * g4[1] + b4[1]);
                    px.z = f2bf((yacc[i][2] - mean) * rstd * g4[2] + b4[2]);
                    px.w = f2bf((yacc[i][3] - mean) * rstd * g4[3] + b4[3]);
                    *(ushort4*)(xs + trow * XS_S + i * 16 + kg * 4) = px;
                }
                __syncthreads();   // xs stable before next layer's Phase A
            }
        }
    }
}

// --------------------------------------------------------------------------
extern "C" void kernel_launch(void* const* d_in, const int* in_sizes, int n_in,
                              void* d_out, int out_size, void* d_ws, size_t ws_size,
                              hipStream_t stream) {
    const float* x    = (const float*)d_in[0];
    const float* mask = (const float*)d_in[1];
    const float* w_in = (const float*)d_in[2];
    const float* b_in = (const float*)d_in[3];
    const float* w_o  = (const float*)d_in[4];
    const float* b_o  = (const float*)d_in[5];
    const float* g1   = (const float*)d_in[6];
    const float* bb1  = (const float*)d_in[7];
    const float* w1   = (const float*)d_in[8];
    const float* b1   = (const float*)d_in[9];
    const float* w2   = (const float*)d_in[10];
    const float* b2   = (const float*)d_in[11];
    const float* g2   = (const float*)d_in[12];
    const float* bb2  = (const float*)d_in[13];

    unsigned short* ws = (unsigned short*)d_ws;   // bf16 weights, 786432 B
    prep_weights_bf16<<<1536, 256, 0, stream>>>(w_in, w_o, w1, w2, ws);
    fused_transformer<<<1024, 512, 0, stream>>>(
        x, mask, b_in, b_o, g1, bb1, b1, b2, g2, bb2,
        ws,                 // in_proj  [L][384][128]
        ws + 98304,         // out_w    [L][128][128]
        ws + 131072,        // ff1_w    [L][512][128]
        ws + 262144,        // ff2_w    [L][128][512]
        (float*)d_out);
}

// Round 9
// 402.338 us; speedup vs baseline: 1.4574x; 1.4574x over previous
//
#include <hip/hip_runtime.h>

// ============================================================================
// Fused 2-layer transformer encoder (B=1024, T=128, D=128, H=8, HD=16, FF=512)
// One workgroup per batch element; bf16 MFMA 16x16x32 for every matmul; fp32
// accumulation/softmax/LN. All matmuls in transposed orientation (Y^T = W*X^T)
// so C-fragments pack as ushort4 column runs.
//
// This revision = the round-1 kernel (352 us dispatch, fastest measured)
// with three independently harness-verified Phase-B upgrades:
//  - zero-shuffle PV: K rows read in permuted order
//    (kt, row m <-> key (kt>>1)*32 + (kt&1)*4 + (m>>2)*8 + (m&3)) so the
//    QK^T C-fragment lands with lane kg holding keys kg*8..kg*8+7 of each
//    32-key step == the PV B-fragment layout. P->LDS staging (32 scalar
//    ds_writes + 2 lgkmcnt + 4 ds_reads per q-tile) is DELETED.
//  - max-free softmax: scores are O(1) (LN'd inputs x 1/sqrt(D) weights),
//    exp cannot overflow; masked keys exp(-1e9)=0. Max pass deleted.
//  - mask staged once into LDS as bf16 (permuted-row indexable).
// Everything else (Phase A fused QKV, by-N C/E with LDS-partial LN, FF in
// 4 chunks of 128) is byte-identical to round 1.
// ============================================================================

typedef __attribute__((ext_vector_type(8))) __bf16 bf16x8;
typedef __attribute__((ext_vector_type(4))) float fx4;

#define MFMA16(a, b, c) __builtin_amdgcn_mfma_f32_16x16x32_bf16((a), (b), (c), 0, 0, 0)

static __device__ __forceinline__ unsigned short f2bf(float f) {
    __bf16 b = (__bf16)f;                       // fptrunc f32->bf16, RTN-even
    return __builtin_bit_cast(unsigned short, b);
}
static __device__ __forceinline__ float bf2f(unsigned short u) {
    return (float)__builtin_bit_cast(__bf16, u);
}
static __device__ __forceinline__ unsigned pk2(float a, float b) {
    return (unsigned)f2bf(a) | ((unsigned)f2bf(b) << 16);
}
static __device__ __forceinline__ bf16x8 mk8(unsigned d0, unsigned d1,
                                             unsigned d2, unsigned d3) {
    union { unsigned u[4]; bf16x8 v; } c;
    c.u[0] = d0; c.u[1] = d1; c.u[2] = d2; c.u[3] = d3;
    return c.v;
}
// element index into a [128][128] tile, 16B-unit XOR swizzle on the row
static __device__ __forceinline__ int swz(int row, int col) {
    return (row << 7) + (col ^ ((row & 7) << 3));
}

// --------------------------------------------------------------------------
// Prep: convert all fp32 weights to bf16 into workspace.
// Segments (elements): in_proj 98304 | out 32768 | ff1 131072 | ff2 131072
// --------------------------------------------------------------------------
extern "C" __global__ void prep_weights_bf16(const float* __restrict__ w_in,
                                             const float* __restrict__ w_out,
                                             const float* __restrict__ w_ff1,
                                             const float* __restrict__ w_ff2,
                                             unsigned short* __restrict__ ws) {
    int i = blockIdx.x * 256 + threadIdx.x;     // grid covers exactly 393216
    float v;
    if (i < 98304)       v = w_in[i];
    else if (i < 131072) v = w_out[i - 98304];
    else if (i < 262144) v = w_ff1[i - 131072];
    else                 v = w_ff2[i - 262144];
    ws[i] = f2bf(v);
}

// --------------------------------------------------------------------------
// Main fused kernel. block = 512 threads = 8 waves. grid = 1024 (one per b).
// __launch_bounds__(512, 2): RA budget 256 regs (round-1-proven config).
// --------------------------------------------------------------------------
extern "C" __global__ void __launch_bounds__(512, 2)
fused_transformer(const float* __restrict__ x,
                  const float* __restrict__ mask,
                  const float* __restrict__ inp_b,
                  const float* __restrict__ out_b,
                  const float* __restrict__ ln1g, const float* __restrict__ ln1b,
                  const float* __restrict__ ff1b, const float* __restrict__ ff2b,
                  const float* __restrict__ ln2g, const float* __restrict__ ln2b,
                  const unsigned short* __restrict__ w_inp,
                  const unsigned short* __restrict__ w_out,
                  const unsigned short* __restrict__ w_ff1,
                  const unsigned short* __restrict__ w_ff2,
                  float* __restrict__ out) {
    // ~137.5 KiB static LDS
    __shared__ __align__(16) unsigned short xs[16384];   // x / LN outputs [t][d]
    __shared__ __align__(16) unsigned short qs[16384];   // q -> o -> FF hidden
    __shared__ __align__(16) unsigned short kvh[32768];  // k | v^T
    __shared__ __align__(16) float lnbuf[2304];          // LN scratch, 9 KiB
    __shared__ __align__(16) unsigned short mlds[128];   // mask (bf16)

    unsigned short* ksb = kvh;             // k  [t][d]
    unsigned short* vtb = kvh + 16384;     // v^T [d][t]
    float2* lnp = (float2*)lnbuf;          // [8][128] {sum, sumsq}
    float2* mrp = lnp + 1024;              // [128] {mean, rstd}

    const int tid = threadIdx.x;
    const int w   = tid >> 6;        // wave 0..7 (== head in phase B)
    const int lid = tid & 63;
    const int l15 = lid & 15;
    const int kg  = lid >> 4;        // k-group 0..3
    const int b   = blockIdx.x;

    // ---- stage x[b] (fp32 global) -> xs (bf16 LDS, swizzled) + mask ----
    const float* xb = x + (size_t)b * 16384;
    #pragma unroll
    for (int i = 0; i < 8; ++i) {
        int e = i * 2048 + tid * 4;
        float4 v4 = *(const float4*)(xb + e);
        int row = e >> 7, col = e & 127;
        ushort4 pk;
        pk.x = f2bf(v4.x); pk.y = f2bf(v4.y); pk.z = f2bf(v4.z); pk.w = f2bf(v4.w);
        *(ushort4*)(xs + swz(row, col)) = pk;
    }
    if (tid < 128) mlds[tid] = f2bf(mask[b * 128 + tid]);
    __syncthreads();

    for (int l = 0; l < 2; ++l) {
        // ========== Phase A: QKV projection (round-1 verbatim) ==============
        // wave w computes exactly head w's q, k (cols w*16..+15) and v.
        {
            const unsigned short* wbase = w_inp + (size_t)l * 49152;
            bf16x8 wq[4], wk[4], wv[4];
            #pragma unroll
            for (int ks = 0; ks < 4; ++ks) {
                wq[ks] = *(const bf16x8*)(wbase + (w * 16 + l15) * 128 + ks * 32 + kg * 8);
                wk[ks] = *(const bf16x8*)(wbase + (128 + w * 16 + l15) * 128 + ks * 32 + kg * 8);
                wv[ks] = *(const bf16x8*)(wbase + (256 + w * 16 + l15) * 128 + ks * 32 + kg * 8);
            }
            fx4 bq = *(const fx4*)(inp_b + l * 384 + w * 16 + kg * 4);
            fx4 bk = *(const fx4*)(inp_b + l * 384 + 128 + w * 16 + kg * 4);
            float bv = inp_b[l * 384 + 256 + w * 16 + l15];
            #pragma unroll
            for (int mt = 0; mt < 8; ++mt) {
                int trow = mt * 16 + l15;
                bf16x8 xf[4];
                #pragma unroll
                for (int ks = 0; ks < 4; ++ks)
                    xf[ks] = *(const bf16x8*)(xs + swz(trow, ks * 32 + kg * 8));
                fx4 aq = bq, ak = bk;
                fx4 av = {bv, bv, bv, bv};
                #pragma unroll
                for (int ks = 0; ks < 4; ++ks) {
                    aq = MFMA16(wq[ks], xf[ks], aq);   // Q^T = Wq * X^T
                    ak = MFMA16(wk[ks], xf[ks], ak);   // K^T = Wk * X^T
                    av = MFMA16(xf[ks], wv[ks], av);   // V   = X * Wv^T
                }
                ushort4 pq;  // q pre-scaled by 1/sqrt(HD)=0.25 (exact in bf16)
                pq.x = f2bf(aq[0] * 0.25f); pq.y = f2bf(aq[1] * 0.25f);
                pq.z = f2bf(aq[2] * 0.25f); pq.w = f2bf(aq[3] * 0.25f);
                *(ushort4*)(qs + swz(trow, w * 16 + kg * 4)) = pq;
                ushort4 pk4;
                pk4.x = f2bf(ak[0]); pk4.y = f2bf(ak[1]);
                pk4.z = f2bf(ak[2]); pk4.w = f2bf(ak[3]);
                *(ushort4*)(ksb + swz(trow, w * 16 + kg * 4)) = pk4;
                ushort4 pv4;
                pv4.x = f2bf(av[0]); pv4.y = f2bf(av[1]);
                pv4.z = f2bf(av[2]); pv4.w = f2bf(av[3]);
                *(ushort4*)(vtb + swz(w * 16 + l15, mt * 16 + kg * 4)) = pv4;
            }
        }
        // wave-local write->read: drain own DS queue (no cross-wave dep)
        asm volatile("s_waitcnt lgkmcnt(0)" ::: "memory");

        // ========== Phase B: attention, zero-shuffle PV, max-free softmax ===
        {
            const int h = w;
            // permuted base row: MFMA row m -> key offset (m>>2)*8 + (m&3)
            const int r0 = ((l15 >> 2) << 3) + (l15 & 3);
            bf16x8 kfr[8];
            #pragma unroll
            for (int kt = 0; kt < 8; ++kt) {
                int krow = (kt >> 1) * 32 + (kt & 1) * 4 + r0;
                bf16x8 f = {};
                if (kg < 2)
                    f = *(const bf16x8*)(ksb + swz(krow, h * 16 + kg * 8));
                else if (kg == 2)
                    f[0] = __builtin_bit_cast(__bf16, mlds[krow]);
                kfr[kt] = f;
            }
            bf16x8 vfr[4];
            #pragma unroll
            for (int s = 0; s < 4; ++s)
                vfr[s] = *(const bf16x8*)(vtb + swz(h * 16 + l15, s * 32 + kg * 8));

            #pragma unroll 1
            for (int qt = 0; qt < 8; ++qt) {
                int qrow = qt * 16 + l15;
                bf16x8 qf = {};
                if (kg < 2) qf = *(const bf16x8*)(qs + swz(qrow, h * 16 + kg * 8));
                else if (kg == 2) qf[0] = (__bf16)1.0f;   // ones column -> adds mask
                // S^T: sc[2s][r]=key s*32+kg*8+r, sc[2s+1][r]=key s*32+kg*8+4+r
                fx4 sc[8];
                #pragma unroll
                for (int kt = 0; kt < 8; ++kt) {
                    fx4 z = {0.f, 0.f, 0.f, 0.f};
                    sc[kt] = MFMA16(kfr[kt], qf, z);
                }
                // max-free softmax: per-lane exp+sum over 32 regs + 2 shuffles
                float sm = 0.f;
                #pragma unroll
                for (int kt = 0; kt < 8; ++kt)
                    #pragma unroll
                    for (int r = 0; r < 4; ++r) {
                        float e = __expf(sc[kt][r]);
                        sc[kt][r] = e;
                        sm += e;
                    }
                sm += __shfl_xor(sm, 16, 64);
                sm += __shfl_xor(sm, 32, 64);
                float inv = 1.f / sm;
                // PV: B-fragment is a pure in-register pack (no LDS, no shfl)
                fx4 oacc = {0.f, 0.f, 0.f, 0.f};
                #pragma unroll
                for (int s = 0; s < 4; ++s) {
                    bf16x8 pf = mk8(pk2(sc[2*s][0],   sc[2*s][1]),
                                    pk2(sc[2*s][2],   sc[2*s][3]),
                                    pk2(sc[2*s+1][0], sc[2*s+1][1]),
                                    pk2(sc[2*s+1][2], sc[2*s+1][3]));
                    oacc = MFMA16(vfr[s], pf, oacc);    // O^T = V^T * P^T (unnorm.)
                }
                ushort4 po;   // normalize at the end (4 muls)
                po.x = f2bf(oacc[0] * inv); po.y = f2bf(oacc[1] * inv);
                po.z = f2bf(oacc[2] * inv); po.w = f2bf(oacc[3] * inv);
                *(ushort4*)(qs + swz(qrow, h * 16 + kg * 4)) = po;
            }
        }
        __syncthreads();

        // ========= Phase C: out-proj + residual + LN1 (round-1 verbatim) ====
        {
            bf16x8 wof[4];
            #pragma unroll
            for (int ks = 0; ks < 4; ++ks)
                wof[ks] = *(const bf16x8*)(w_out + (size_t)(l * 128 + w * 16 + l15) * 128
                                           + ks * 32 + kg * 8);
            fx4 ob4 = *(const fx4*)(out_b + l * 128 + w * 16 + kg * 4);
            fx4 acc[8];
            #pragma unroll
            for (int tt = 0; tt < 8; ++tt) {
                int trow = tt * 16 + l15;
                fx4 a = {0.f, 0.f, 0.f, 0.f};
                #pragma unroll
                for (int ks = 0; ks < 4; ++ks) {
                    bf16x8 of = *(const bf16x8*)(qs + swz(trow, ks * 32 + kg * 8));
                    a = MFMA16(wof[ks], of, a);     // OUT^T = Wout * O^T
                }
                ushort4 rx = *(const ushort4*)(xs + swz(trow, w * 16 + kg * 4));
                a[0] += ob4[0] + bf2f(rx.x); a[1] += ob4[1] + bf2f(rx.y);
                a[2] += ob4[2] + bf2f(rx.z); a[3] += ob4[3] + bf2f(rx.w);
                acc[tt] = a;
                float s  = a[0] + a[1] + a[2] + a[3];
                float qq = a[0]*a[0] + a[1]*a[1] + a[2]*a[2] + a[3]*a[3];
                s  += __shfl_xor(s, 16, 64);  qq += __shfl_xor(qq, 16, 64);
                s  += __shfl_xor(s, 32, 64);  qq += __shfl_xor(qq, 32, 64);
                if (lid < 16) { float2 p; p.x = s; p.y = qq; lnp[w * 128 + trow] = p; }
            }
            __syncthreads();
            if (tid < 128) {
                float ms = 0.f, mq = 0.f;
                #pragma unroll
                for (int wv = 0; wv < 8; ++wv) {
                    float2 p = lnp[wv * 128 + tid];
                    ms += p.x; mq += p.y;
                }
                float mean = ms * 0.0078125f;
                float var  = mq * 0.0078125f - mean * mean;
                float2 m2; m2.x = mean; m2.y = rsqrtf(var + 1e-5f);
                mrp[tid] = m2;
            }
            __syncthreads();
            fx4 g4 = *(const fx4*)(ln1g + l * 128 + w * 16 + kg * 4);
            fx4 b4 = *(const fx4*)(ln1b + l * 128 + w * 16 + kg * 4);
            #pragma unroll
            for (int tt = 0; tt < 8; ++tt) {
                int trow = tt * 16 + l15;
                float2 m2 = mrp[trow];
                ushort4 px;
                px.x = f2bf((acc[tt][0] - m2.x) * m2.y * g4[0] + b4[0]);
                px.y = f2bf((acc[tt][1] - m2.x) * m2.y * g4[1] + b4[1]);
                px.z = f2bf((acc[tt][2] - m2.x) * m2.y * g4[2] + b4[2]);
                px.w = f2bf((acc[tt][3] - m2.x) * m2.y * g4[3] + b4[3]);
                *(ushort4*)(xs + swz(trow, w * 16 + kg * 4)) = px;
            }
        }
        __syncthreads();

        // ======== Phase D: FF, 4 K-chunks of 128 (round-1 verbatim) =========
        fx4 yacc[8];
        {
            fx4 z = {0.f, 0.f, 0.f, 0.f};
            #pragma unroll
            for (int tt = 0; tt < 8; ++tt) yacc[tt] = z;
        }
        #pragma unroll 1
        for (int c = 0; c < 4; ++c) {
            {   // FF1: H^T = W1 * X^T, + bias + relu -> qs (packed)
                bf16x8 w1f[4];
                int frow = l * 512 + c * 128 + w * 16;
                #pragma unroll
                for (int ks = 0; ks < 4; ++ks)
                    w1f[ks] = *(const bf16x8*)(w_ff1 + (size_t)(frow + l15) * 128
                                               + ks * 32 + kg * 8);
                fx4 b1f = *(const fx4*)(ff1b + frow + kg * 4);
                #pragma unroll
                for (int tt = 0; tt < 8; ++tt) {
                    int trow = tt * 16 + l15;
                    bf16x8 xf[4];
                    #pragma unroll
                    for (int ks = 0; ks < 4; ++ks)
                        xf[ks] = *(const bf16x8*)(xs + swz(trow, ks * 32 + kg * 8));
                    fx4 a = b1f;
                    #pragma unroll
                    for (int ks = 0; ks < 4; ++ks)
                        a = MFMA16(w1f[ks], xf[ks], a);
                    ushort4 ph;
                    ph.x = f2bf(fmaxf(a[0], 0.f)); ph.y = f2bf(fmaxf(a[1], 0.f));
                    ph.z = f2bf(fmaxf(a[2], 0.f)); ph.w = f2bf(fmaxf(a[3], 0.f));
                    *(ushort4*)(qs + swz(trow, w * 16 + kg * 4)) = ph;
                }
            }
            __syncthreads();
            {   // FF2 partial accumulate: Y^T = W2 * H^T
                bf16x8 w2f[4];
                #pragma unroll
                for (int k8 = 0; k8 < 4; ++k8)
                    w2f[k8] = *(const bf16x8*)(w_ff2 + (size_t)(l * 128 + w * 16 + l15) * 512
                                               + c * 128 + k8 * 32 + kg * 8);
                #pragma unroll
                for (int tt = 0; tt < 8; ++tt) {
                    int trow = tt * 16 + l15;
                    #pragma unroll
                    for (int k8 = 0; k8 < 4; ++k8) {
                        bf16x8 hf = *(const bf16x8*)(qs + swz(trow, k8 * 32 + kg * 8));
                        yacc[tt] = MFMA16(w2f[k8], hf, yacc[tt]);
                    }
                }
            }
            if (c < 3) __syncthreads();   // protect hidden before next chunk
        }

        // ========= Phase E: + bias + residual + LN2 (round-1 verbatim) ======
        {
            fx4 fb4 = *(const fx4*)(ff2b + l * 128 + w * 16 + kg * 4);
            #pragma unroll
            for (int tt = 0; tt < 8; ++tt) {
                int trow = tt * 16 + l15;
                ushort4 rx = *(const ushort4*)(xs + swz(trow, w * 16 + kg * 4));
                yacc[tt][0] += fb4[0] + bf2f(rx.x);
                yacc[tt][1] += fb4[1] + bf2f(rx.y);
                yacc[tt][2] += fb4[2] + bf2f(rx.z);
                yacc[tt][3] += fb4[3] + bf2f(rx.w);
                fx4 a = yacc[tt];
                float s  = a[0] + a[1] + a[2] + a[3];
                float qq = a[0]*a[0] + a[1]*a[1] + a[2]*a[2] + a[3]*a[3];
                s  += __shfl_xor(s, 16, 64);  qq += __shfl_xor(qq, 16, 64);
                s  += __shfl_xor(s, 32, 64);  qq += __shfl_xor(qq, 32, 64);
                if (lid < 16) { float2 p; p.x = s; p.y = qq; lnp[w * 128 + trow] = p; }
            }
            __syncthreads();
            if (tid < 128) {
                float ms = 0.f, mq = 0.f;
                #pragma unroll
                for (int wv = 0; wv < 8; ++wv) {
                    float2 p = lnp[wv * 128 + tid];
                    ms += p.x; mq += p.y;
                }
                float mean = ms * 0.0078125f;
                float var  = mq * 0.0078125f - mean * mean;
                float2 m2; m2.x = mean; m2.y = rsqrtf(var + 1e-5f);
                mrp[tid] = m2;
            }
            __syncthreads();
            fx4 g4 = *(const fx4*)(ln2g + l * 128 + w * 16 + kg * 4);
            fx4 b4 = *(const fx4*)(ln2b + l * 128 + w * 16 + kg * 4);
            if (l == 1) {   // final layer: fp32 output, packed float4 stores
                float* op = out + (size_t)b * 16384;
                #pragma unroll
                for (int tt = 0; tt < 8; ++tt) {
                    int trow = tt * 16 + l15;
                    float2 m2 = mrp[trow];
                    float4 v4;
                    v4.x = (yacc[tt][0] - m2.x) * m2.y * g4[0] + b4[0];
                    v4.y = (yacc[tt][1] - m2.x) * m2.y * g4[1] + b4[1];
                    v4.z = (yacc[tt][2] - m2.x) * m2.y * g4[2] + b4[2];
                    v4.w = (yacc[tt][3] - m2.x) * m2.y * g4[3] + b4[3];
                    *(float4*)(op + (size_t)trow * 128 + w * 16 + kg * 4) = v4;
                }
            } else {
                #pragma unroll
                for (int tt = 0; tt < 8; ++tt) {
                    int trow = tt * 16 + l15;
                    float2 m2 = mrp[trow];
                    ushort4 px;
                    px.x = f2bf((yacc[tt][0] - m2.x) * m2.y * g4[0] + b4[0]);
                    px.y = f2bf((yacc[tt][1] - m2.x) * m2.y * g4[1] + b4[1]);
                    px.z = f2bf((yacc[tt][2] - m2.x) * m2.y * g4[2] + b4[2]);
                    px.w = f2bf((yacc[tt][3] - m2.x) * m2.y * g4[3] + b4[3]);
                    *(ushort4*)(xs + swz(trow, w * 16 + kg * 4)) = px;
                }
                __syncthreads();   // xs stable before next layer's Phase A
            }
        }
    }
}

// --------------------------------------------------------------------------
extern "C" void kernel_launch(void* const* d_in, const int* in_sizes, int n_in,
                              void* d_out, int out_size, void* d_ws, size_t ws_size,
                              hipStream_t stream) {
    const float* x    = (const float*)d_in[0];
    const float* mask = (const float*)d_in[1];
    const float* w_in = (const float*)d_in[2];
    const float* b_in = (const float*)d_in[3];
    const float* w_o  = (const float*)d_in[4];
    const float* b_o  = (const float*)d_in[5];
    const float* g1   = (const float*)d_in[6];
    const float* bb1  = (const float*)d_in[7];
    const float* w1   = (const float*)d_in[8];
    const float* b1   = (const float*)d_in[9];
    const float* w2   = (const float*)d_in[10];
    const float* b2   = (const float*)d_in[11];
    const float* g2   = (const float*)d_in[12];
    const float* bb2  = (const float*)d_in[13];

    unsigned short* ws = (unsigned short*)d_ws;   // bf16 weights, 786432 B
    prep_weights_bf16<<<1536, 256, 0, stream>>>(w_in, w_o, w1, w2, ws);
    fused_transformer<<<1024, 512, 0, stream>>>(
        x, mask, b_in, b_o, g1, bb1, b1, b2, g2, bb2,
        ws,                 // in_proj  [L][384][128]
        ws + 98304,         // out_w    [L][128][128]
        ws + 131072,        // ff1_w    [L][512][128]
        ws + 262144,        // ff2_w    [L][128][512]
        (float*)d_out);
}